// Round 3
// baseline (277.097 us; speedup 1.0000x reference)
//
#include <hip/hip_runtime.h>

#define BB 2
#define NN 16384
#define CC 64
#define SS 4096
#define KK 32
#define R2 0.16f   // RADIUS^2

typedef __bf16 bf16x8 __attribute__((ext_vector_type(8)));
typedef float  f32x4  __attribute__((ext_vector_type(4)));

#define MFMA(a, b, c) __builtin_amdgcn_mfma_f32_16x16x32_bf16((a), (b), (c), 0, 0, 0)

static __device__ __forceinline__ ushort f2bf(float f) {
    __bf16 h = (__bf16)f;
    return *(ushort*)&h;
}

// workspace section offsets (bytes)
#define WS_IDX    0          // idx_ws:  2*4096*32*4   = 1,048,576
#define WS_PTS4   1048576    // pts4:    2*16384*16    =   524,288
#define WS_FEAT   1572864    // feat_nc: 2*16384*64*2  = 4,194,304
#define WS_W1T    5767168    // 64*96*2   = 12,288
#define WS_W2T    5779456    // 64*64*2   =  8,192
#define WS_W3T    5787648    // 128*64*2  = 16,384
#define WS_CTR    5804032    // 4 bytes

// prep_misc index ranges
#define T_PTS   (BB * NN)                  // 32768
#define T_W1    (T_PTS + 64 * 96)          // +6144
#define T_W2    (T_W1 + 64 * 64)           // +4096
#define T_W3    (T_W2 + 128 * 64)          // +8192
#define T_NXYZ  (T_W3 + BB * SS * 3)       // +24576
#define T_SIDX  (T_NXYZ + BB * SS)         // +8192
#define T_ALL   (T_SIDX + 1)               // +1 (counter)

// ---------------------------------------------------------------------------
// prep_misc: pts4=(x,y,z,|x|^2); bf16 weight transposes; coalesced new_xyz
// copy; samp_idx; work-queue counter init.
// ---------------------------------------------------------------------------
__global__ __launch_bounds__(256) void prep_misc(
        const float* __restrict__ xyz, const float* __restrict__ W1,
        const float* __restrict__ W2, const float* __restrict__ W3,
        float4* __restrict__ pts4, ushort* __restrict__ W1t,
        ushort* __restrict__ W2t, ushort* __restrict__ W3t,
        float* __restrict__ out_xyz, float* __restrict__ out_sidx,
        int* __restrict__ counter) {
    const int t = blockIdx.x * 256 + threadIdx.x;
    if (t < T_PTS) {
        const float* p = xyz + (size_t)t * 3;
        const float x = p[0], y = p[1], z = p[2];
        pts4[t] = make_float4(x, y, z, x * x + y * y + z * z);
    } else if (t < T_W1) {
        const int i = t - T_PTS;
        const int n = i / 96, k = i - n * 96;
        float v = 0.0f;
        if (k < 64) v = W1[(3 + k) * 64 + n];
        else if (k < 67) v = W1[(k - 64) * 64 + n];
        W1t[n * 96 + k] = f2bf(v);
    } else if (t < T_W2) {
        const int i = t - T_W1;
        const int n = i >> 6, k = i & 63;
        W2t[n * 64 + k] = f2bf(W2[k * 64 + n]);
    } else if (t < T_W3) {
        const int i = t - T_W2;
        const int n = i >> 6, k = i & 63;
        W3t[n * 64 + k] = f2bf(W3[k * 128 + n]);
    } else if (t < T_NXYZ) {
        const int i = t - T_W3;              // new_xyz = xyz[:, :SS] copy
        const int b = i / (SS * 3), j = i - b * (SS * 3);
        out_xyz[i] = xyz[(size_t)b * NN * 3 + j];
    } else if (t < T_SIDX) {
        const int i = t - T_NXYZ;
        out_sidx[i] = (float)(i & (SS - 1));
    } else if (t < T_ALL) {
        *counter = 0;
    }
}

// ---------------------------------------------------------------------------
// prep_feat: [B][C][N] fp32 -> [B][N][C] bf16 (coalesced reads per channel).
// ---------------------------------------------------------------------------
__global__ __launch_bounds__(256) void prep_feat(const float* __restrict__ feat,
                                                 ushort* __restrict__ feat_nc) {
    const int t = blockIdx.x * 256 + threadIdx.x;   // 0 .. BB*NN-1
    const int b = t >> 14, n = t & (NN - 1);
    const float* fb = feat + (size_t)b * CC * NN + n;
    ushort* dst = feat_nc + (size_t)t * 64;
    #pragma unroll
    for (int c8 = 0; c8 < 8; ++c8) {
        uint u[4];
        #pragma unroll
        for (int j = 0; j < 4; ++j) {
            const float f0 = fb[(size_t)(c8 * 8 + 2 * j) * NN];
            const float f1 = fb[(size_t)(c8 * 8 + 2 * j + 1) * NN];
            u[j] = (uint)f2bf(f0) | ((uint)f2bf(f1) << 16);
        }
        *(uint4*)(dst + c8 * 8) = make_uint4(u[0], u[1], u[2], u[3]);
    }
}

// ---------------------------------------------------------------------------
// bq: persistent waves + dynamic queue; 256-pt chunks with next-chunk
// prefetch issued before the ballot-dependent break (hides L2 latency).
// ---------------------------------------------------------------------------
__global__ __launch_bounds__(256) void bq_kernel(const float4* __restrict__ pts4,
                                                 int* __restrict__ idx_ws,
                                                 int* __restrict__ counter) {
    const int w = threadIdx.x >> 6, lane = threadIdx.x & 63;
    __shared__ int hits[4][KK];
    int* hit = hits[w];
    const unsigned long long ltmask = (1ull << lane) - 1ull;

    for (;;) {
        int sg = 0;
        if (lane == 0) sg = atomicAdd(counter, 1);
        sg = __builtin_amdgcn_readfirstlane(sg);
        if (sg >= BB * SS) return;
        const int b = sg >> 12, s = sg & (SS - 1);
        const float4* pb = pts4 + (size_t)b * NN;
        const float4 c = pb[s];

        float4 p0 = pb[lane], p1 = pb[64 + lane];
        float4 p2 = pb[128 + lane], p3 = pb[192 + lane];
        int cnt = 0;
        for (int base = 0;;) {
            const int nb = base + 256;
            const bool last = nb >= NN;
            const int pf = last ? 0 : nb;
            // prefetch next chunk (independent of this chunk's ballot)
            const float4 q0 = pb[pf + lane], q1 = pb[pf + 64 + lane];
            const float4 q2 = pb[pf + 128 + lane], q3 = pb[pf + 192 + lane];

            const float d0 = c.w + p0.w - 2.0f * (c.x * p0.x + c.y * p0.y + c.z * p0.z);
            const float d1 = c.w + p1.w - 2.0f * (c.x * p1.x + c.y * p1.y + c.z * p1.z);
            const float d2 = c.w + p2.w - 2.0f * (c.x * p2.x + c.y * p2.y + c.z * p2.z);
            const float d3 = c.w + p3.w - 2.0f * (c.x * p3.x + c.y * p3.y + c.z * p3.z);
            const bool h0 = d0 < R2, h1 = d1 < R2, h2 = d2 < R2, h3 = d3 < R2;
            const unsigned long long m0 = __ballot(h0), m1 = __ballot(h1);
            const unsigned long long m2 = __ballot(h2), m3 = __ballot(h3);
            const int c0 = __popcll(m0), c1 = __popcll(m1);
            const int c2 = __popcll(m2), c3 = __popcll(m3);
            if (h0) { const int p = cnt + __popcll(m0 & ltmask);                if (p < KK) hit[p] = base + lane; }
            if (h1) { const int p = cnt + c0 + __popcll(m1 & ltmask);           if (p < KK) hit[p] = base + 64 + lane; }
            if (h2) { const int p = cnt + c0 + c1 + __popcll(m2 & ltmask);      if (p < KK) hit[p] = base + 128 + lane; }
            if (h3) { const int p = cnt + c0 + c1 + c2 + __popcll(m3 & ltmask); if (p < KK) hit[p] = base + 192 + lane; }
            cnt += c0 + c1 + c2 + c3;
            if (cnt >= KK || last) break;
            base = nb;
            p0 = q0; p1 = q1; p2 = q2; p3 = q3;
        }
        if (lane < KK) {
            const int v = (cnt == 0) ? 0 : ((lane < cnt) ? hit[lane] : hit[0]);
            idx_ws[(size_t)sg * KK + lane] = v;
        }
    }
}

// ---------------------------------------------------------------------------
// mlp: 1 block = 8 consecutive s (2 per wave); weights streamed from L1;
// h1/h2 folded into gbuf (program-order-safe within a wave); outputs staged
// in LDS then stored coalesced. XCD swizzle: xcd 0-3 -> batch 0, 4-7 -> 1.
// ---------------------------------------------------------------------------
__global__ __launch_bounds__(256, 4) void mlp_kernel(
        const float4* __restrict__ pts4, const ushort* __restrict__ feat_nc,
        const ushort* __restrict__ W1t, const ushort* __restrict__ W2t,
        const ushort* __restrict__ W3t,
        const float* __restrict__ b1, const float* __restrict__ b2,
        const float* __restrict__ b3,
        const int* __restrict__ idx_ws, float* __restrict__ out_feat) {
    const int w = threadIdx.x >> 6, lane = threadIdx.x & 63;
    const int quad = lane >> 4, mrow = lane & 15;

    __shared__ __align__(16) ushort ldsA[4][32 * 104];  // g / h1 / h2 per wave
    __shared__ float stage[128 * 9];                    // [ch][8 s] +1 pad
    ushort* gbuf = ldsA[w];

    // block -> (batch, s-tile) with XCD swizzle for feat L2 locality
    const int xcd = blockIdx.x & 7;
    const int slot = blockIdx.x >> 3;           // 0..127
    const int b = xcd >> 2;
    const int tile = (xcd & 3) * 128 + slot;    // 0..511
    const int s0 = tile * 8;

    float bias1[4], bias2[4], bias3[8];
    #pragma unroll
    for (int nt = 0; nt < 4; ++nt) {
        bias1[nt] = b1[nt * 16 + mrow];
        bias2[nt] = b2[nt * 16 + mrow];
    }
    #pragma unroll
    for (int nt = 0; nt < 8; ++nt) bias3[nt] = b3[nt * 16 + mrow];

    #pragma unroll
    for (int gi = 0; gi < 2; ++gi) {
        const int sl = w + gi * 4;              // 0..7 within tile
        const int s = s0 + sl;
        const int grp = b * SS + s;

        // ---- gather: feat bf16 rows + rel_xyz + zero pad --------------------
        {
            const int m = lane & 31, half = lane >> 5;
            const int id = idx_ws[(size_t)grp * KK + m];
            const ushort* src = feat_nc + ((size_t)b * NN + id) * 64 + half * 32;
            ushort* dst = gbuf + m * 104 + half * 32;
            #pragma unroll
            for (int i = 0; i < 4; ++i)
                *(uint4*)(dst + i * 8) = *(const uint4*)(src + i * 8);
            if (half == 0) {
                const float4 p = pts4[(size_t)b * NN + id];
                const float4 cc = pts4[(size_t)b * NN + s];
                bf16x8 rel = {(__bf16)(p.x - cc.x), (__bf16)(p.y - cc.y),
                              (__bf16)(p.z - cc.z), (__bf16)0.f,
                              (__bf16)0.f, (__bf16)0.f, (__bf16)0.f, (__bf16)0.f};
                *(bf16x8*)(gbuf + m * 104 + 64) = rel;
                *(uint4*)(gbuf + m * 104 + 88) = make_uint4(0, 0, 0, 0);
            } else {
                *(uint4*)(gbuf + m * 104 + 72) = make_uint4(0, 0, 0, 0);
                *(uint4*)(gbuf + m * 104 + 80) = make_uint4(0, 0, 0, 0);
            }
        }

        // ---- layer 1: [32x96]x[96x64], W1 streamed from L1 ------------------
        {
            f32x4 acc[2][4];
            #pragma unroll
            for (int mt = 0; mt < 2; ++mt)
                #pragma unroll
                for (int nt = 0; nt < 4; ++nt)
                    acc[mt][nt] = (f32x4){bias1[nt], bias1[nt], bias1[nt], bias1[nt]};
            #pragma unroll
            for (int ks = 0; ks < 3; ++ks) {
                const bf16x8 a0 = *(const bf16x8*)(gbuf + mrow * 104 + ks * 32 + quad * 8);
                const bf16x8 a1 = *(const bf16x8*)(gbuf + (16 + mrow) * 104 + ks * 32 + quad * 8);
                #pragma unroll
                for (int nt = 0; nt < 4; ++nt) {
                    const bf16x8 wf = *(const bf16x8*)(W1t + (nt * 16 + mrow) * 96 + ks * 32 + quad * 8);
                    acc[0][nt] = MFMA(a0, wf, acc[0][nt]);
                    acc[1][nt] = MFMA(a1, wf, acc[1][nt]);
                }
            }
            #pragma unroll
            for (int mt = 0; mt < 2; ++mt)
                #pragma unroll
                for (int nt = 0; nt < 4; ++nt)
                    #pragma unroll
                    for (int r = 0; r < 4; ++r)
                        gbuf[(mt * 16 + quad * 4 + r) * 104 + nt * 16 + mrow] =
                            f2bf(fmaxf(acc[mt][nt][r], 0.0f));
        }

        // ---- layer 2: [32x64]x[64x64] ---------------------------------------
        {
            f32x4 acc[2][4];
            #pragma unroll
            for (int mt = 0; mt < 2; ++mt)
                #pragma unroll
                for (int nt = 0; nt < 4; ++nt)
                    acc[mt][nt] = (f32x4){bias2[nt], bias2[nt], bias2[nt], bias2[nt]};
            #pragma unroll
            for (int ks = 0; ks < 2; ++ks) {
                const bf16x8 a0 = *(const bf16x8*)(gbuf + mrow * 104 + ks * 32 + quad * 8);
                const bf16x8 a1 = *(const bf16x8*)(gbuf + (16 + mrow) * 104 + ks * 32 + quad * 8);
                #pragma unroll
                for (int nt = 0; nt < 4; ++nt) {
                    const bf16x8 wf = *(const bf16x8*)(W2t + (nt * 16 + mrow) * 64 + ks * 32 + quad * 8);
                    acc[0][nt] = MFMA(a0, wf, acc[0][nt]);
                    acc[1][nt] = MFMA(a1, wf, acc[1][nt]);
                }
            }
            #pragma unroll
            for (int mt = 0; mt < 2; ++mt)
                #pragma unroll
                for (int nt = 0; nt < 4; ++nt)
                    #pragma unroll
                    for (int r = 0; r < 4; ++r)
                        gbuf[(mt * 16 + quad * 4 + r) * 104 + nt * 16 + mrow] =
                            f2bf(fmaxf(acc[mt][nt][r], 0.0f));
        }

        // ---- layer 3: [32x64]x[64x128] in two n-halves, fused maxpool -------
        #pragma unroll
        for (int nh = 0; nh < 2; ++nh) {
            f32x4 acc[2][4];
            #pragma unroll
            for (int mt = 0; mt < 2; ++mt)
                #pragma unroll
                for (int ntl = 0; ntl < 4; ++ntl) {
                    const float bv = bias3[nh * 4 + ntl];
                    acc[mt][ntl] = (f32x4){bv, bv, bv, bv};
                }
            #pragma unroll
            for (int ks = 0; ks < 2; ++ks) {
                const bf16x8 a0 = *(const bf16x8*)(gbuf + mrow * 104 + ks * 32 + quad * 8);
                const bf16x8 a1 = *(const bf16x8*)(gbuf + (16 + mrow) * 104 + ks * 32 + quad * 8);
                #pragma unroll
                for (int ntl = 0; ntl < 4; ++ntl) {
                    const bf16x8 wf = *(const bf16x8*)(
                        W3t + ((nh * 4 + ntl) * 16 + mrow) * 64 + ks * 32 + quad * 8);
                    acc[0][ntl] = MFMA(a0, wf, acc[0][ntl]);
                    acc[1][ntl] = MFMA(a1, wf, acc[1][ntl]);
                }
            }
            #pragma unroll
            for (int ntl = 0; ntl < 4; ++ntl) {
                const f32x4 v0 = acc[0][ntl], v1 = acc[1][ntl];
                float mx = fmaxf(fmaxf(v0[0], v0[1]), fmaxf(v0[2], v0[3]));
                mx = fmaxf(mx, fmaxf(fmaxf(v1[0], v1[1]), fmaxf(v1[2], v1[3])));
                mx = fmaxf(mx, __shfl_xor(mx, 16));
                mx = fmaxf(mx, __shfl_xor(mx, 32));
                mx = fmaxf(mx, 0.0f);
                if (quad == ntl)
                    stage[((nh * 4 + ntl) * 16 + mrow) * 9 + sl] = mx;
            }
        }
    }
    __syncthreads();

    // ---- coalesced store: 128 ch x 8 s, 16B per thread ----------------------
    {
        const int ch = threadIdx.x >> 1;
        const int j0 = (threadIdx.x & 1) * 4;
        const float* r = stage + ch * 9 + j0;
        const float4 v = make_float4(r[0], r[1], r[2], r[3]);
        *(float4*)(out_feat + ((size_t)b * 128 + ch) * SS + s0 + j0) = v;
    }
}

// ---------------------------------------------------------------------------
extern "C" void kernel_launch(void* const* d_in, const int* in_sizes, int n_in,
                              void* d_out, int out_size, void* d_ws, size_t ws_size,
                              hipStream_t stream) {
    const float* xyz  = (const float*)d_in[0];
    const float* feat = (const float*)d_in[1];
    const float* W1   = (const float*)d_in[2];
    const float* b1   = (const float*)d_in[3];
    const float* W2   = (const float*)d_in[4];
    const float* b2   = (const float*)d_in[5];
    const float* W3   = (const float*)d_in[6];
    const float* b3   = (const float*)d_in[7];

    float* out      = (float*)d_out;
    float* out_xyz  = out;                               // [2,4096,3]
    float* out_feat = out + (size_t)BB * SS * 3;         // [2,128,4096]
    float* out_sidx = out_feat + (size_t)BB * 128 * SS;  // [2,4096]

    char* ws = (char*)d_ws;
    int*    idx_ws  = (int*)(ws + WS_IDX);
    float4* pts4    = (float4*)(ws + WS_PTS4);
    ushort* feat_nc = (ushort*)(ws + WS_FEAT);
    ushort* W1t     = (ushort*)(ws + WS_W1T);
    ushort* W2t     = (ushort*)(ws + WS_W2T);
    ushort* W3t     = (ushort*)(ws + WS_W3T);
    int*    counter = (int*)(ws + WS_CTR);

    prep_misc<<<(T_ALL + 255) / 256, 256, 0, stream>>>(
        xyz, W1, W2, W3, pts4, W1t, W2t, W3t, out_xyz, out_sidx, counter);
    prep_feat<<<BB * NN / 256, 256, 0, stream>>>(feat, feat_nc);
    bq_kernel<<<1024, 256, 0, stream>>>(pts4, idx_ws, counter);
    mlp_kernel<<<1024, 256, 0, stream>>>(pts4, feat_nc, W1t, W2t, W3t,
                                         b1, b2, b3, idx_ws, out_feat);
}

// Round 4
// 183.136 us; speedup vs baseline: 1.5131x; 1.5131x over previous
//
#include <hip/hip_runtime.h>

#define BB 2
#define NN 16384
#define CC 64
#define SS 4096
#define KK 32
#define R2 0.16f   // RADIUS^2

typedef __bf16 bf16x8 __attribute__((ext_vector_type(8)));
typedef float  f32x4  __attribute__((ext_vector_type(4)));

#define MFMA(a, b, c) __builtin_amdgcn_mfma_f32_16x16x32_bf16((a), (b), (c), 0, 0, 0)

static __device__ __forceinline__ ushort f2bf(float f) {
    __bf16 h = (__bf16)f;
    return *(ushort*)&h;
}

// workspace section offsets (bytes)
#define WS_IDX    0          // idx_ws:  2*4096*32*4   = 1,048,576
#define WS_PTS4   1048576    // pts4:    2*16384*16    =   524,288
#define WS_FEAT   1572864    // feat_nc: 2*16384*64*2  = 4,194,304
#define WS_W1T    5767168    // 64*96*2   = 12,288
#define WS_W2T    5779456    // 64*64*2   =  8,192
#define WS_W3T    5787648    // 128*64*2  = 16,384
#define WS_MOUT   5804032    // mlp_out bf16 [b][s][128] = 2,097,152  (end 7.9MB)

// prep_misc index ranges
#define T_PTS   (BB * NN)                  // 32768
#define T_W1    (T_PTS + 64 * 96)
#define T_W2    (T_W1 + 64 * 64)
#define T_W3    (T_W2 + 128 * 64)
#define T_NXYZ  (T_W3 + BB * SS * 3)
#define T_SIDX  (T_NXYZ + BB * SS)

// ---------------------------------------------------------------------------
// prep_misc: pts4=(x,y,z,|x|^2); bf16 weight transposes; coalesced new_xyz
// copy; samp_idx.
// ---------------------------------------------------------------------------
__global__ __launch_bounds__(256) void prep_misc(
        const float* __restrict__ xyz, const float* __restrict__ W1,
        const float* __restrict__ W2, const float* __restrict__ W3,
        float4* __restrict__ pts4, ushort* __restrict__ W1t,
        ushort* __restrict__ W2t, ushort* __restrict__ W3t,
        float* __restrict__ out_xyz, float* __restrict__ out_sidx) {
    const int t = blockIdx.x * 256 + threadIdx.x;
    if (t < T_PTS) {
        const float* p = xyz + (size_t)t * 3;
        const float x = p[0], y = p[1], z = p[2];
        pts4[t] = make_float4(x, y, z, x * x + y * y + z * z);
    } else if (t < T_W1) {
        const int i = t - T_PTS;
        const int n = i / 96, k = i - n * 96;
        float v = 0.0f;
        if (k < 64) v = W1[(3 + k) * 64 + n];
        else if (k < 67) v = W1[(k - 64) * 64 + n];
        W1t[n * 96 + k] = f2bf(v);
    } else if (t < T_W2) {
        const int i = t - T_W1;
        const int n = i >> 6, k = i & 63;
        W2t[n * 64 + k] = f2bf(W2[k * 64 + n]);
    } else if (t < T_W3) {
        const int i = t - T_W2;
        const int n = i >> 6, k = i & 63;
        W3t[n * 64 + k] = f2bf(W3[k * 128 + n]);
    } else if (t < T_NXYZ) {
        const int i = t - T_W3;              // new_xyz = xyz[:, :SS] copy
        const int b = i / (SS * 3), j = i - b * (SS * 3);
        out_xyz[i] = xyz[(size_t)b * NN * 3 + j];
    } else if (t < T_SIDX) {
        const int i = t - T_NXYZ;
        out_sidx[i] = (float)(i & (SS - 1));
    }
}

// ---------------------------------------------------------------------------
// prep_feat: [B][C][N] fp32 -> [B][N][C] bf16 (coalesced reads per channel).
// ---------------------------------------------------------------------------
__global__ __launch_bounds__(256) void prep_feat(const float* __restrict__ feat,
                                                 ushort* __restrict__ feat_nc) {
    const int t = blockIdx.x * 256 + threadIdx.x;   // 0 .. BB*NN-1
    const int b = t >> 14, n = t & (NN - 1);
    const float* fb = feat + (size_t)b * CC * NN + n;
    ushort* dst = feat_nc + (size_t)t * 64;
    #pragma unroll
    for (int c8 = 0; c8 < 8; ++c8) {
        uint u[4];
        #pragma unroll
        for (int j = 0; j < 4; ++j) {
            const float f0 = fb[(size_t)(c8 * 8 + 2 * j) * NN];
            const float f1 = fb[(size_t)(c8 * 8 + 2 * j + 1) * NN];
            u[j] = (uint)f2bf(f0) | ((uint)f2bf(f1) << 16);
        }
        *(uint4*)(dst + c8 * 8) = make_uint4(u[0], u[1], u[2], u[3]);
    }
}

// ---------------------------------------------------------------------------
// bq: STATIC one wave per centroid (8192 waves, no atomics — R3's single
// global counter serialized at ~43cyc/RMW = 147us). 256-pt chunks with
// next-chunk prefetch issued before the ballot-dependent break.
// ---------------------------------------------------------------------------
__global__ __launch_bounds__(256) void bq_kernel(const float4* __restrict__ pts4,
                                                 int* __restrict__ idx_ws) {
    const int w = threadIdx.x >> 6, lane = threadIdx.x & 63;
    const int sg = blockIdx.x * 4 + w;       // 0 .. BB*SS-1
    const int b = sg >> 12, s = sg & (SS - 1);

    __shared__ int hits[4][KK];
    int* hit = hits[w];
    const unsigned long long ltmask = (1ull << lane) - 1ull;

    const float4* pb = pts4 + (size_t)b * NN;
    const float4 c = pb[s];

    float4 p0 = pb[lane], p1 = pb[64 + lane];
    float4 p2 = pb[128 + lane], p3 = pb[192 + lane];
    int cnt = 0;
    for (int base = 0;;) {
        const int nb = base + 256;
        const bool last = nb >= NN;
        const int pf = last ? 0 : nb;
        // prefetch next chunk (independent of this chunk's ballot/break)
        const float4 q0 = pb[pf + lane], q1 = pb[pf + 64 + lane];
        const float4 q2 = pb[pf + 128 + lane], q3 = pb[pf + 192 + lane];

        const float d0 = c.w + p0.w - 2.0f * (c.x * p0.x + c.y * p0.y + c.z * p0.z);
        const float d1 = c.w + p1.w - 2.0f * (c.x * p1.x + c.y * p1.y + c.z * p1.z);
        const float d2 = c.w + p2.w - 2.0f * (c.x * p2.x + c.y * p2.y + c.z * p2.z);
        const float d3 = c.w + p3.w - 2.0f * (c.x * p3.x + c.y * p3.y + c.z * p3.z);
        const bool h0 = d0 < R2, h1 = d1 < R2, h2 = d2 < R2, h3 = d3 < R2;
        const unsigned long long m0 = __ballot(h0), m1 = __ballot(h1);
        const unsigned long long m2 = __ballot(h2), m3 = __ballot(h3);
        const int c0 = __popcll(m0), c1 = __popcll(m1);
        const int c2 = __popcll(m2), c3 = __popcll(m3);
        if (h0) { const int p = cnt + __popcll(m0 & ltmask);                if (p < KK) hit[p] = base + lane; }
        if (h1) { const int p = cnt + c0 + __popcll(m1 & ltmask);           if (p < KK) hit[p] = base + 64 + lane; }
        if (h2) { const int p = cnt + c0 + c1 + __popcll(m2 & ltmask);      if (p < KK) hit[p] = base + 128 + lane; }
        if (h3) { const int p = cnt + c0 + c1 + c2 + __popcll(m3 & ltmask); if (p < KK) hit[p] = base + 192 + lane; }
        cnt += c0 + c1 + c2 + c3;
        if (cnt >= KK || last) break;
        base = nb;
        p0 = q0; p1 = q1; p2 = q2; p3 = q3;
    }
    if (lane < KK) {
        const int v = (cnt == 0) ? 0 : ((lane < cnt) ? hit[lane] : hit[0]);
        idx_ws[(size_t)sg * KK + lane] = v;
    }
}

// ---------------------------------------------------------------------------
// mlp: EXACT R2 structure (measured 57us): one wave per group (grid-stride),
// W1/W2 B-frags pinned in registers, per-wave LDS, fused bias+maxpool.
// ONLY change: store [b][s][ch] bf16 contiguous to ws (kills the 128MB
// write-amplification of the strided scatter store; transpose kernel below).
// ---------------------------------------------------------------------------
__global__ __launch_bounds__(256, 2) void mlp_kernel(
        const float4* __restrict__ pts4, const ushort* __restrict__ feat_nc,
        const ushort* __restrict__ W1t, const ushort* __restrict__ W2t,
        const ushort* __restrict__ W3t,
        const float* __restrict__ b1, const float* __restrict__ b2,
        const float* __restrict__ b3,
        const int* __restrict__ idx_ws, ushort* __restrict__ mlp_out) {
    const int w = threadIdx.x >> 6, lane = threadIdx.x & 63;
    const int quad = lane >> 4, mrow = lane & 15;

    __shared__ __align__(16) ushort ldsA[4][32 * 104];  // g, reused as h2
    __shared__ __align__(16) ushort ldsB[4][32 * 72];   // h1
    ushort* gbuf = ldsA[w];
    ushort* hbuf = ldsB[w];

    bf16x8 w1f[4][3], w2f[4][2];
    #pragma unroll
    for (int nt = 0; nt < 4; ++nt) {
        #pragma unroll
        for (int ks = 0; ks < 3; ++ks)
            w1f[nt][ks] = *(const bf16x8*)(W1t + (nt * 16 + mrow) * 96 + ks * 32 + quad * 8);
        #pragma unroll
        for (int ks = 0; ks < 2; ++ks)
            w2f[nt][ks] = *(const bf16x8*)(W2t + (nt * 16 + mrow) * 64 + ks * 32 + quad * 8);
    }
    float bias1[4], bias2[4], bias3[8];
    #pragma unroll
    for (int nt = 0; nt < 4; ++nt) {
        bias1[nt] = b1[nt * 16 + mrow];
        bias2[nt] = b2[nt * 16 + mrow];
    }
    #pragma unroll
    for (int nt = 0; nt < 8; ++nt) bias3[nt] = b3[nt * 16 + mrow];

    const int wid = blockIdx.x * 4 + w;
    for (int grp = wid; grp < BB * SS; grp += gridDim.x * 4) {
        const int b = grp >> 12, s = grp & (SS - 1);

        // ---- gather: features (bf16 copy) + rel_xyz + zero pad -------------
        {
            const int m = lane & 31, half = lane >> 5;
            const int id = idx_ws[(size_t)grp * KK + m];
            const ushort* src = feat_nc + ((size_t)b * NN + id) * 64 + half * 32;
            ushort* dst = gbuf + m * 104 + half * 32;
            #pragma unroll
            for (int i = 0; i < 4; ++i)
                *(uint4*)(dst + i * 8) = *(const uint4*)(src + i * 8);
            if (half == 0) {
                const float4 p = pts4[(size_t)b * NN + id];
                const float4 cc = pts4[(size_t)b * NN + s];
                bf16x8 rel = {(__bf16)(p.x - cc.x), (__bf16)(p.y - cc.y),
                              (__bf16)(p.z - cc.z), (__bf16)0.f,
                              (__bf16)0.f, (__bf16)0.f, (__bf16)0.f, (__bf16)0.f};
                *(bf16x8*)(gbuf + m * 104 + 64) = rel;
                *(uint4*)(gbuf + m * 104 + 88) = make_uint4(0, 0, 0, 0);
            } else {
                *(uint4*)(gbuf + m * 104 + 72) = make_uint4(0, 0, 0, 0);
                *(uint4*)(gbuf + m * 104 + 80) = make_uint4(0, 0, 0, 0);
            }
        }

        // ---- layer 1: [32x96]x[96x64] ---------------------------------------
        f32x4 acc1[2][4];
        #pragma unroll
        for (int mt = 0; mt < 2; ++mt)
            #pragma unroll
            for (int nt = 0; nt < 4; ++nt)
                acc1[mt][nt] = (f32x4){bias1[nt], bias1[nt], bias1[nt], bias1[nt]};
        #pragma unroll
        for (int ks = 0; ks < 3; ++ks) {
            const bf16x8 a0 = *(const bf16x8*)(gbuf + mrow * 104 + ks * 32 + quad * 8);
            const bf16x8 a1 = *(const bf16x8*)(gbuf + (16 + mrow) * 104 + ks * 32 + quad * 8);
            #pragma unroll
            for (int nt = 0; nt < 4; ++nt) {
                acc1[0][nt] = MFMA(a0, w1f[nt][ks], acc1[0][nt]);
                acc1[1][nt] = MFMA(a1, w1f[nt][ks], acc1[1][nt]);
            }
        }
        #pragma unroll
        for (int mt = 0; mt < 2; ++mt)
            #pragma unroll
            for (int nt = 0; nt < 4; ++nt)
                #pragma unroll
                for (int r = 0; r < 4; ++r)
                    hbuf[(mt * 16 + quad * 4 + r) * 72 + nt * 16 + mrow] =
                        f2bf(fmaxf(acc1[mt][nt][r], 0.0f));

        // ---- layer 2: [32x64]x[64x64] ---------------------------------------
        f32x4 acc2[2][4];
        #pragma unroll
        for (int mt = 0; mt < 2; ++mt)
            #pragma unroll
            for (int nt = 0; nt < 4; ++nt)
                acc2[mt][nt] = (f32x4){bias2[nt], bias2[nt], bias2[nt], bias2[nt]};
        #pragma unroll
        for (int ks = 0; ks < 2; ++ks) {
            const bf16x8 a0 = *(const bf16x8*)(hbuf + mrow * 72 + ks * 32 + quad * 8);
            const bf16x8 a1 = *(const bf16x8*)(hbuf + (16 + mrow) * 72 + ks * 32 + quad * 8);
            #pragma unroll
            for (int nt = 0; nt < 4; ++nt) {
                acc2[0][nt] = MFMA(a0, w2f[nt][ks], acc2[0][nt]);
                acc2[1][nt] = MFMA(a1, w2f[nt][ks], acc2[1][nt]);
            }
        }
        #pragma unroll
        for (int mt = 0; mt < 2; ++mt)
            #pragma unroll
            for (int nt = 0; nt < 4; ++nt)
                #pragma unroll
                for (int r = 0; r < 4; ++r)
                    gbuf[(mt * 16 + quad * 4 + r) * 104 + nt * 16 + mrow] =
                        f2bf(fmaxf(acc2[mt][nt][r], 0.0f));

        // ---- layer 3: [32x64]x[64x128], W3 streamed from L1 ----------------
        f32x4 acc3[2][8];
        #pragma unroll
        for (int mt = 0; mt < 2; ++mt)
            #pragma unroll
            for (int nt = 0; nt < 8; ++nt)
                acc3[mt][nt] = (f32x4){bias3[nt], bias3[nt], bias3[nt], bias3[nt]};
        #pragma unroll
        for (int ks = 0; ks < 2; ++ks) {
            const bf16x8 a0 = *(const bf16x8*)(gbuf + mrow * 104 + ks * 32 + quad * 8);
            const bf16x8 a1 = *(const bf16x8*)(gbuf + (16 + mrow) * 104 + ks * 32 + quad * 8);
            #pragma unroll
            for (int nt = 0; nt < 8; ++nt) {
                const bf16x8 w3f = *(const bf16x8*)(W3t + (nt * 16 + mrow) * 64 + ks * 32 + quad * 8);
                acc3[0][nt] = MFMA(a0, w3f, acc3[0][nt]);
                acc3[1][nt] = MFMA(a1, w3f, acc3[1][nt]);
            }
        }

        // ---- maxpool + relu; store [b][s][ch] bf16 contiguous --------------
        #pragma unroll
        for (int nt = 0; nt < 8; ++nt) {
            const f32x4 v0 = acc3[0][nt], v1 = acc3[1][nt];
            float mx = fmaxf(fmaxf(v0[0], v0[1]), fmaxf(v0[2], v0[3]));
            mx = fmaxf(mx, fmaxf(fmaxf(v1[0], v1[1]), fmaxf(v1[2], v1[3])));
            mx = fmaxf(mx, __shfl_xor(mx, 16));
            mx = fmaxf(mx, __shfl_xor(mx, 32));
            mx = fmaxf(mx, 0.0f);
            if (quad == 0)
                mlp_out[(size_t)grp * 128 + nt * 16 + mrow] = f2bf(mx);
        }
    }
}

// ---------------------------------------------------------------------------
// tr_kernel: [b][s][ch] bf16 -> [b][ch][s] fp32, 32s x 128ch LDS tile,
// fully coalesced both directions.
// ---------------------------------------------------------------------------
__global__ __launch_bounds__(256) void tr_kernel(const ushort* __restrict__ mlp_out,
                                                 float* __restrict__ out_feat) {
    __shared__ float tile[32][129];
    const int blk = blockIdx.x;            // 0..255
    const int b = blk >> 7;
    const int s0 = (blk & 127) * 32;
    const int t = threadIdx.x;
    #pragma unroll
    for (int k = 0; k < 16; ++k) {
        const int i = t + k * 256;         // 0..4095
        const int r = i >> 7, c = i & 127;
        const uint u = mlp_out[((size_t)b * SS + s0 + r) * 128 + c];
        tile[r][c] = __uint_as_float(u << 16);
    }
    __syncthreads();
    #pragma unroll
    for (int k = 0; k < 16; ++k) {
        const int j = t + k * 256;
        const int ch = j >> 5, so = j & 31;
        out_feat[((size_t)b * 128 + ch) * SS + s0 + so] = tile[so][ch];
    }
}

// ---------------------------------------------------------------------------
extern "C" void kernel_launch(void* const* d_in, const int* in_sizes, int n_in,
                              void* d_out, int out_size, void* d_ws, size_t ws_size,
                              hipStream_t stream) {
    const float* xyz  = (const float*)d_in[0];
    const float* feat = (const float*)d_in[1];
    const float* W1   = (const float*)d_in[2];
    const float* b1   = (const float*)d_in[3];
    const float* W2   = (const float*)d_in[4];
    const float* b2   = (const float*)d_in[5];
    const float* W3   = (const float*)d_in[6];
    const float* b3   = (const float*)d_in[7];

    float* out      = (float*)d_out;
    float* out_xyz  = out;                               // [2,4096,3]
    float* out_feat = out + (size_t)BB * SS * 3;         // [2,128,4096]
    float* out_sidx = out_feat + (size_t)BB * 128 * SS;  // [2,4096]

    char* ws = (char*)d_ws;
    int*    idx_ws  = (int*)(ws + WS_IDX);
    float4* pts4    = (float4*)(ws + WS_PTS4);
    ushort* feat_nc = (ushort*)(ws + WS_FEAT);
    ushort* W1t     = (ushort*)(ws + WS_W1T);
    ushort* W2t     = (ushort*)(ws + WS_W2T);
    ushort* W3t     = (ushort*)(ws + WS_W3T);
    ushort* mlp_out = (ushort*)(ws + WS_MOUT);

    prep_misc<<<(T_SIDX + 255) / 256, 256, 0, stream>>>(
        xyz, W1, W2, W3, pts4, W1t, W2t, W3t, out_xyz, out_sidx);
    prep_feat<<<BB * NN / 256, 256, 0, stream>>>(feat, feat_nc);
    bq_kernel<<<BB * SS / 4, 256, 0, stream>>>(pts4, idx_ws);
    mlp_kernel<<<1024, 256, 0, stream>>>(pts4, feat_nc, W1t, W2t, W3t,
                                         b1, b2, b3, idx_ws, mlp_out);
    tr_kernel<<<BB * SS / 32, 256, 0, stream>>>(mlp_out, out_feat);
}

// Round 5
// 181.890 us; speedup vs baseline: 1.5234x; 1.0069x over previous
//
#include <hip/hip_runtime.h>

#define BB 2
#define NN 16384
#define CC 64
#define SS 4096
#define KK 32
#define R2 0.16f   // RADIUS^2

typedef __bf16 bf16x8 __attribute__((ext_vector_type(8)));
typedef float  f32x4  __attribute__((ext_vector_type(4)));

#define MFMA(a, b, c) __builtin_amdgcn_mfma_f32_16x16x32_bf16((a), (b), (c), 0, 0, 0)

static __device__ __forceinline__ ushort f2bf(float f) {
    __bf16 h = (__bf16)f;
    return *(ushort*)&h;
}

// workspace section offsets (bytes)
#define WS_IDX    0          // idx_ws:  2*4096*32*4   = 1,048,576
#define WS_PTS4   1048576    // pts4:    2*16384*16    =   524,288
#define WS_FEAT   1572864    // feat_nc: 2*16384*64*2  = 4,194,304
#define WS_W1T    5767168    // 64*96*2   = 12,288
#define WS_W2T    5779456    // 64*64*2   =  8,192
#define WS_W3T    5787648    // 128*64*2  = 16,384
#define WS_MOUT   5804032    // mlp_out bf16 [b][s][128] = 2,097,152
#define WS_CTR    7901184    // 32 counters, 128B apart = 4,096   (end ~7.905MB)

// prep_misc index ranges
#define T_PTS   (BB * NN)
#define T_W1    (T_PTS + 64 * 96)
#define T_W2    (T_W1 + 64 * 64)
#define T_W3    (T_W2 + 128 * 64)
#define T_NXYZ  (T_W3 + BB * SS * 3)
#define T_SIDX  (T_NXYZ + BB * SS)
#define T_CTR   (T_SIDX + 1024)

// ---------------------------------------------------------------------------
// prep_misc: pts4=(x,y,z,|x|^2); bf16 weight transposes; coalesced new_xyz
// copy; samp_idx; zero the bq work-queue counters.
// ---------------------------------------------------------------------------
__global__ __launch_bounds__(256) void prep_misc(
        const float* __restrict__ xyz, const float* __restrict__ W1,
        const float* __restrict__ W2, const float* __restrict__ W3,
        float4* __restrict__ pts4, ushort* __restrict__ W1t,
        ushort* __restrict__ W2t, ushort* __restrict__ W3t,
        float* __restrict__ out_xyz, float* __restrict__ out_sidx,
        int* __restrict__ ctrs) {
    const int t = blockIdx.x * 256 + threadIdx.x;
    if (t < T_PTS) {
        const float* p = xyz + (size_t)t * 3;
        const float x = p[0], y = p[1], z = p[2];
        pts4[t] = make_float4(x, y, z, x * x + y * y + z * z);
    } else if (t < T_W1) {
        const int i = t - T_PTS;
        const int n = i / 96, k = i - n * 96;
        float v = 0.0f;
        if (k < 64) v = W1[(3 + k) * 64 + n];
        else if (k < 67) v = W1[(k - 64) * 64 + n];
        W1t[n * 96 + k] = f2bf(v);
    } else if (t < T_W2) {
        const int i = t - T_W1;
        const int n = i >> 6, k = i & 63;
        W2t[n * 64 + k] = f2bf(W2[k * 64 + n]);
    } else if (t < T_W3) {
        const int i = t - T_W2;
        const int n = i >> 6, k = i & 63;
        W3t[n * 64 + k] = f2bf(W3[k * 128 + n]);
    } else if (t < T_NXYZ) {
        const int i = t - T_W3;              // new_xyz = xyz[:, :SS] copy
        const int b = i / (SS * 3), j = i - b * (SS * 3);
        out_xyz[i] = xyz[(size_t)b * NN * 3 + j];
    } else if (t < T_SIDX) {
        const int i = t - T_NXYZ;
        out_sidx[i] = (float)(i & (SS - 1));
    } else if (t < T_CTR) {
        ctrs[t - T_SIDX] = 0;
    }
}

// ---------------------------------------------------------------------------
// prep_feat: [B][C][N] fp32 -> [B][N][C] bf16 (coalesced reads per channel).
// ---------------------------------------------------------------------------
__global__ __launch_bounds__(256) void prep_feat(const float* __restrict__ feat,
                                                 ushort* __restrict__ feat_nc) {
    const int t = blockIdx.x * 256 + threadIdx.x;   // 0 .. BB*NN-1
    const int b = t >> 14, n = t & (NN - 1);
    const float* fb = feat + (size_t)b * CC * NN + n;
    ushort* dst = feat_nc + (size_t)t * 64;
    #pragma unroll
    for (int c8 = 0; c8 < 8; ++c8) {
        uint u[4];
        #pragma unroll
        for (int j = 0; j < 4; ++j) {
            const float f0 = fb[(size_t)(c8 * 8 + 2 * j) * NN];
            const float f1 = fb[(size_t)(c8 * 8 + 2 * j + 1) * NN];
            u[j] = (uint)f2bf(f0) | ((uint)f2bf(f1) << 16);
        }
        *(uint4*)(dst + c8 * 8) = make_uint4(u[0], u[1], u[2], u[3]);
    }
}

// ---------------------------------------------------------------------------
// bq: dynamic work queue over 32 DISTRIBUTED counters (128B apart; chunk=2;
// plain-read guard so exhausted counters cost a load, not an RMW). Kills the
// static-tail straggle (R4: 55us) without R3's single-counter serialization
// (147us). Scan itself: 256-pt chunks with next-chunk prefetch.
// ---------------------------------------------------------------------------
__global__ __launch_bounds__(256) void bq_kernel(const float4* __restrict__ pts4,
                                                 int* __restrict__ idx_ws,
                                                 int* __restrict__ ctrs) {
    const int w = threadIdx.x >> 6, lane = threadIdx.x & 63;
    __shared__ int hits[4][KK];
    int* hit = hits[w];
    const unsigned long long ltmask = (1ull << lane) - 1ull;
    const int wid = blockIdx.x * 4 + w;

    for (int t = 0; t < 32; ++t) {
        const int ci = (wid + t) & 31;        // counter ci owns groups [ci*256, ci*256+256)
        int* cp = ctrs + ci * 32;             // 128B apart
        for (;;) {
            int v = 128;
            if (lane == 0) {
                if (*(volatile int*)cp < 128)  // monotone counter: stale read is an
                    v = atomicAdd(cp, 1);      // under-estimate -> safe to try RMW
            }
            v = __builtin_amdgcn_readfirstlane(v);
            if (v >= 128) break;
            #pragma unroll 1
            for (int u = 0; u < 2; ++u) {
                const int sg = ci * 256 + v * 2 + u;
                const int b = sg >> 12, s = sg & (SS - 1);
                const float4* pb = pts4 + (size_t)b * NN;
                const float4 c = pb[s];

                float4 p0 = pb[lane], p1 = pb[64 + lane];
                float4 p2 = pb[128 + lane], p3 = pb[192 + lane];
                int cnt = 0;
                for (int base = 0;;) {
                    const int nb = base + 256;
                    const bool last = nb >= NN;
                    const int pf = last ? 0 : nb;
                    const float4 q0 = pb[pf + lane], q1 = pb[pf + 64 + lane];
                    const float4 q2 = pb[pf + 128 + lane], q3 = pb[pf + 192 + lane];

                    const float d0 = c.w + p0.w - 2.0f * (c.x * p0.x + c.y * p0.y + c.z * p0.z);
                    const float d1 = c.w + p1.w - 2.0f * (c.x * p1.x + c.y * p1.y + c.z * p1.z);
                    const float d2 = c.w + p2.w - 2.0f * (c.x * p2.x + c.y * p2.y + c.z * p2.z);
                    const float d3 = c.w + p3.w - 2.0f * (c.x * p3.x + c.y * p3.y + c.z * p3.z);
                    const bool h0 = d0 < R2, h1 = d1 < R2, h2 = d2 < R2, h3 = d3 < R2;
                    const unsigned long long m0 = __ballot(h0), m1 = __ballot(h1);
                    const unsigned long long m2 = __ballot(h2), m3 = __ballot(h3);
                    const int c0 = __popcll(m0), c1 = __popcll(m1);
                    const int c2 = __popcll(m2), c3 = __popcll(m3);
                    if (h0) { const int p = cnt + __popcll(m0 & ltmask);                if (p < KK) hit[p] = base + lane; }
                    if (h1) { const int p = cnt + c0 + __popcll(m1 & ltmask);           if (p < KK) hit[p] = base + 64 + lane; }
                    if (h2) { const int p = cnt + c0 + c1 + __popcll(m2 & ltmask);      if (p < KK) hit[p] = base + 128 + lane; }
                    if (h3) { const int p = cnt + c0 + c1 + c2 + __popcll(m3 & ltmask); if (p < KK) hit[p] = base + 192 + lane; }
                    cnt += c0 + c1 + c2 + c3;
                    if (cnt >= KK || last) break;
                    base = nb;
                    p0 = q0; p1 = q1; p2 = q2; p3 = q3;
                }
                if (lane < KK) {
                    const int vv = (cnt == 0) ? 0 : ((lane < cnt) ? hit[lane] : hit[0]);
                    idx_ws[(size_t)sg * KK + lane] = vv;
                }
            }
        }
    }
}

// ---------------------------------------------------------------------------
// mlp: one wave per group, 2 groups/wave. W1 frags pinned; W2/W3 streamed
// (L1-hot). h1/h2 folded into gbuf (in-order per-wave LDS). Software
// pipeline: next group's idx prefetched during layer1, its feature rows +
// pts during layers 2-3. XCD swizzle: xcd 0-3 -> batch 0, 4-7 -> batch 1
// (perf heuristic only; index coverage is exact regardless of mapping).
// ---------------------------------------------------------------------------
__global__ __launch_bounds__(256, 2) void mlp_kernel(
        const float4* __restrict__ pts4, const ushort* __restrict__ feat_nc,
        const ushort* __restrict__ W1t, const ushort* __restrict__ W2t,
        const ushort* __restrict__ W3t,
        const float* __restrict__ b1, const float* __restrict__ b2,
        const float* __restrict__ b3,
        const int* __restrict__ idx_ws, ushort* __restrict__ mlp_out) {
    const int w = threadIdx.x >> 6, lane = threadIdx.x & 63;
    const int quad = lane >> 4, mrow = lane & 15;
    const int m = lane & 31, half = lane >> 5;

    __shared__ __align__(16) ushort ldsA[4][32 * 104];   // g -> h1 -> h2 per wave
    ushort* gbuf = ldsA[w];

    // W1 fragments pinned (first consumer after staging -> hide its latency)
    bf16x8 w1f[4][3];
    #pragma unroll
    for (int nt = 0; nt < 4; ++nt)
        #pragma unroll
        for (int ks = 0; ks < 3; ++ks)
            w1f[nt][ks] = *(const bf16x8*)(W1t + (nt * 16 + mrow) * 96 + ks * 32 + quad * 8);
    float bias1[4], bias2[4], bias3[8];
    #pragma unroll
    for (int nt = 0; nt < 4; ++nt) {
        bias1[nt] = b1[nt * 16 + mrow];
        bias2[nt] = b2[nt * 16 + mrow];
    }
    #pragma unroll
    for (int nt = 0; nt < 8; ++nt) bias3[nt] = b3[nt * 16 + mrow];

    // block -> (batch, s) swizzle
    const int xcd = blockIdx.x & 7;
    const int j = blockIdx.x >> 3;               // 0..127
    const int b = xcd >> 2;
    const int s0 = (xcd & 3) * 1024 + j * 8 + w * 2;   // 2 consecutive s per wave
    const int grp0 = b * SS + s0;
    const float4* pbase = pts4 + (size_t)b * NN;
    const ushort* fbase = feat_nc + (size_t)b * NN * 64;

    // prologue: stage group 0 into registers
    int sid = idx_ws[(size_t)grp0 * KK + m];
    uint4 stg[4];
    {
        const ushort* src = fbase + (size_t)sid * 64 + half * 32;
        #pragma unroll
        for (int i = 0; i < 4; ++i) stg[i] = *(const uint4*)(src + i * 8);
    }
    float4 sp = pbase[sid];
    float4 scc = pbase[s0];

    int sid1;
    uint4 stg1[4];
    float4 sp1, scc1;

    #pragma unroll
    for (int gi = 0; gi < 2; ++gi) {
        const int grp = grp0 + gi;

        // ---- stage registers -> LDS ----------------------------------------
        {
            ushort* dst = gbuf + m * 104 + half * 32;
            #pragma unroll
            for (int i = 0; i < 4; ++i) *(uint4*)(dst + i * 8) = stg[i];
            if (half == 0) {
                bf16x8 rel = {(__bf16)(sp.x - scc.x), (__bf16)(sp.y - scc.y),
                              (__bf16)(sp.z - scc.z), (__bf16)0.f,
                              (__bf16)0.f, (__bf16)0.f, (__bf16)0.f, (__bf16)0.f};
                *(bf16x8*)(gbuf + m * 104 + 64) = rel;
                *(uint4*)(gbuf + m * 104 + 88) = make_uint4(0, 0, 0, 0);
            } else {
                *(uint4*)(gbuf + m * 104 + 72) = make_uint4(0, 0, 0, 0);
                *(uint4*)(gbuf + m * 104 + 80) = make_uint4(0, 0, 0, 0);
            }
        }

        // prefetch next group's idx (overlaps layer 1)
        if (gi == 0) sid1 = idx_ws[(size_t)(grp0 + 1) * KK + m];

        // ---- layer 1: [32x96]x[96x64], W1 pinned; h1 overwrites g ----------
        {
            f32x4 acc[2][4];
            #pragma unroll
            for (int mt = 0; mt < 2; ++mt)
                #pragma unroll
                for (int nt = 0; nt < 4; ++nt)
                    acc[mt][nt] = (f32x4){bias1[nt], bias1[nt], bias1[nt], bias1[nt]};
            #pragma unroll
            for (int ks = 0; ks < 3; ++ks) {
                const bf16x8 a0 = *(const bf16x8*)(gbuf + mrow * 104 + ks * 32 + quad * 8);
                const bf16x8 a1 = *(const bf16x8*)(gbuf + (16 + mrow) * 104 + ks * 32 + quad * 8);
                #pragma unroll
                for (int nt = 0; nt < 4; ++nt) {
                    acc[0][nt] = MFMA(a0, w1f[nt][ks], acc[0][nt]);
                    acc[1][nt] = MFMA(a1, w1f[nt][ks], acc[1][nt]);
                }
            }
            #pragma unroll
            for (int mt = 0; mt < 2; ++mt)
                #pragma unroll
                for (int nt = 0; nt < 4; ++nt)
                    #pragma unroll
                    for (int r = 0; r < 4; ++r)
                        gbuf[(mt * 16 + quad * 4 + r) * 104 + nt * 16 + mrow] =
                            f2bf(fmaxf(acc[mt][nt][r], 0.0f));
        }

        // prefetch next group's feature rows + pts (overlaps layers 2-3)
        if (gi == 0) {
            const ushort* src1 = fbase + (size_t)sid1 * 64 + half * 32;
            #pragma unroll
            for (int i = 0; i < 4; ++i) stg1[i] = *(const uint4*)(src1 + i * 8);
            sp1 = pbase[sid1];
            scc1 = pbase[s0 + 1];
        }

        // ---- layer 2: [32x64]x[64x64], W2 streamed; h2 overwrites h1 -------
        {
            f32x4 acc[2][4];
            #pragma unroll
            for (int mt = 0; mt < 2; ++mt)
                #pragma unroll
                for (int nt = 0; nt < 4; ++nt)
                    acc[mt][nt] = (f32x4){bias2[nt], bias2[nt], bias2[nt], bias2[nt]};
            #pragma unroll
            for (int ks = 0; ks < 2; ++ks) {
                const bf16x8 a0 = *(const bf16x8*)(gbuf + mrow * 104 + ks * 32 + quad * 8);
                const bf16x8 a1 = *(const bf16x8*)(gbuf + (16 + mrow) * 104 + ks * 32 + quad * 8);
                #pragma unroll
                for (int nt = 0; nt < 4; ++nt) {
                    const bf16x8 wf = *(const bf16x8*)(W2t + (nt * 16 + mrow) * 64 + ks * 32 + quad * 8);
                    acc[0][nt] = MFMA(a0, wf, acc[0][nt]);
                    acc[1][nt] = MFMA(a1, wf, acc[1][nt]);
                }
            }
            #pragma unroll
            for (int mt = 0; mt < 2; ++mt)
                #pragma unroll
                for (int nt = 0; nt < 4; ++nt)
                    #pragma unroll
                    for (int r = 0; r < 4; ++r)
                        gbuf[(mt * 16 + quad * 4 + r) * 104 + nt * 16 + mrow] =
                            f2bf(fmaxf(acc[mt][nt][r], 0.0f));
        }

        // ---- layer 3: [32x64]x[64x128], W3 streamed; fused maxpool ---------
        {
            f32x4 acc[2][8];
            #pragma unroll
            for (int mt = 0; mt < 2; ++mt)
                #pragma unroll
                for (int nt = 0; nt < 8; ++nt)
                    acc[mt][nt] = (f32x4){bias3[nt], bias3[nt], bias3[nt], bias3[nt]};
            #pragma unroll
            for (int ks = 0; ks < 2; ++ks) {
                const bf16x8 a0 = *(const bf16x8*)(gbuf + mrow * 104 + ks * 32 + quad * 8);
                const bf16x8 a1 = *(const bf16x8*)(gbuf + (16 + mrow) * 104 + ks * 32 + quad * 8);
                #pragma unroll
                for (int nt = 0; nt < 8; ++nt) {
                    const bf16x8 wf = *(const bf16x8*)(W3t + (nt * 16 + mrow) * 64 + ks * 32 + quad * 8);
                    acc[0][nt] = MFMA(a0, wf, acc[0][nt]);
                    acc[1][nt] = MFMA(a1, wf, acc[1][nt]);
                }
            }
            #pragma unroll
            for (int nt = 0; nt < 8; ++nt) {
                const f32x4 v0 = acc[0][nt], v1 = acc[1][nt];
                float mx = fmaxf(fmaxf(v0[0], v0[1]), fmaxf(v0[2], v0[3]));
                mx = fmaxf(mx, fmaxf(fmaxf(v1[0], v1[1]), fmaxf(v1[2], v1[3])));
                mx = fmaxf(mx, __shfl_xor(mx, 16));
                mx = fmaxf(mx, __shfl_xor(mx, 32));
                mx = fmaxf(mx, 0.0f);
                if (quad == 0)
                    mlp_out[(size_t)grp * 128 + nt * 16 + mrow] = f2bf(mx);
            }
        }

        // rotate staging
        if (gi == 0) {
            sid = sid1;
            #pragma unroll
            for (int i = 0; i < 4; ++i) stg[i] = stg1[i];
            sp = sp1; scc = scc1;
        }
    }
}

// ---------------------------------------------------------------------------
// tr_kernel: [b][s][ch] bf16 -> [b][ch][s] fp32, 32s x 128ch LDS tile.
// ---------------------------------------------------------------------------
__global__ __launch_bounds__(256) void tr_kernel(const ushort* __restrict__ mlp_out,
                                                 float* __restrict__ out_feat) {
    __shared__ float tile[32][129];
    const int blk = blockIdx.x;            // 0..255
    const int b = blk >> 7;
    const int s0 = (blk & 127) * 32;
    const int t = threadIdx.x;
    #pragma unroll
    for (int k = 0; k < 16; ++k) {
        const int i = t + k * 256;
        const int r = i >> 7, c = i & 127;
        const uint u = mlp_out[((size_t)b * SS + s0 + r) * 128 + c];
        tile[r][c] = __uint_as_float(u << 16);
    }
    __syncthreads();
    #pragma unroll
    for (int k = 0; k < 16; ++k) {
        const int jj = t + k * 256;
        const int ch = jj >> 5, so = jj & 31;
        out_feat[((size_t)b * 128 + ch) * SS + s0 + so] = tile[so][ch];
    }
}

// ---------------------------------------------------------------------------
extern "C" void kernel_launch(void* const* d_in, const int* in_sizes, int n_in,
                              void* d_out, int out_size, void* d_ws, size_t ws_size,
                              hipStream_t stream) {
    const float* xyz  = (const float*)d_in[0];
    const float* feat = (const float*)d_in[1];
    const float* W1   = (const float*)d_in[2];
    const float* b1   = (const float*)d_in[3];
    const float* W2   = (const float*)d_in[4];
    const float* b2   = (const float*)d_in[5];
    const float* W3   = (const float*)d_in[6];
    const float* b3   = (const float*)d_in[7];

    float* out      = (float*)d_out;
    float* out_xyz  = out;                               // [2,4096,3]
    float* out_feat = out + (size_t)BB * SS * 3;         // [2,128,4096]
    float* out_sidx = out_feat + (size_t)BB * 128 * SS;  // [2,4096]

    char* ws = (char*)d_ws;
    int*    idx_ws  = (int*)(ws + WS_IDX);
    float4* pts4    = (float4*)(ws + WS_PTS4);
    ushort* feat_nc = (ushort*)(ws + WS_FEAT);
    ushort* W1t     = (ushort*)(ws + WS_W1T);
    ushort* W2t     = (ushort*)(ws + WS_W2T);
    ushort* W3t     = (ushort*)(ws + WS_W3T);
    ushort* mlp_out = (ushort*)(ws + WS_MOUT);
    int*    ctrs    = (int*)(ws + WS_CTR);

    prep_misc<<<(T_CTR + 255) / 256, 256, 0, stream>>>(
        xyz, W1, W2, W3, pts4, W1t, W2t, W3t, out_xyz, out_sidx, ctrs);
    prep_feat<<<BB * NN / 256, 256, 0, stream>>>(feat, feat_nc);
    bq_kernel<<<1024, 256, 0, stream>>>(pts4, idx_ws, ctrs);
    mlp_kernel<<<1024, 256, 0, stream>>>(pts4, feat_nc, W1t, W2t, W3t,
                                         b1, b2, b3, idx_ws, mlp_out);
    tr_kernel<<<BB * SS / 32, 256, 0, stream>>>(mlp_out, out_feat);
}

// Round 6
// 175.853 us; speedup vs baseline: 1.5757x; 1.0343x over previous
//
#include <hip/hip_runtime.h>

#define BB 2
#define NN 16384
#define CC 64
#define SS 4096
#define KK 32
#define R2 0.16f   // RADIUS^2

typedef __bf16 bf16x8 __attribute__((ext_vector_type(8)));
typedef float  f32x4  __attribute__((ext_vector_type(4)));

#define MFMA(a, b, c) __builtin_amdgcn_mfma_f32_16x16x32_bf16((a), (b), (c), 0, 0, 0)

static __device__ __forceinline__ ushort f2bf(float f) {
    __bf16 h = (__bf16)f;
    return *(ushort*)&h;
}

// workspace section offsets (bytes)
#define WS_IDX    0          // idx_ws:  2*4096*32*4   = 1,048,576
#define WS_PTS4   1048576    // pts4:    2*16384*16    =   524,288
#define WS_FEAT   1572864    // feat_nc: 2*16384*64*2  = 4,194,304
#define WS_W1T    5767168    // 64*96*2   = 12,288
#define WS_W2T    5779456    // 64*64*2   =  8,192
#define WS_W3T    5787648    // 128*64*2  = 16,384

// prep_misc index ranges
#define T_PTS   (BB * NN)
#define T_W1    (T_PTS + 64 * 96)
#define T_W2    (T_W1 + 64 * 64)
#define T_W3    (T_W2 + 128 * 64)
#define T_NXYZ  (T_W3 + BB * SS * 3)
#define T_SIDX  (T_NXYZ + BB * SS)

// ---------------------------------------------------------------------------
// prep_misc: pts4=(x,y,z,|x|^2); bf16 weight transposes; coalesced new_xyz
// copy; samp_idx.
// ---------------------------------------------------------------------------
__global__ __launch_bounds__(256) void prep_misc(
        const float* __restrict__ xyz, const float* __restrict__ W1,
        const float* __restrict__ W2, const float* __restrict__ W3,
        float4* __restrict__ pts4, ushort* __restrict__ W1t,
        ushort* __restrict__ W2t, ushort* __restrict__ W3t,
        float* __restrict__ out_xyz, float* __restrict__ out_sidx) {
    const int t = blockIdx.x * 256 + threadIdx.x;
    if (t < T_PTS) {
        const float* p = xyz + (size_t)t * 3;
        const float x = p[0], y = p[1], z = p[2];
        pts4[t] = make_float4(x, y, z, x * x + y * y + z * z);
    } else if (t < T_W1) {
        const int i = t - T_PTS;
        const int n = i / 96, k = i - n * 96;
        float v = 0.0f;
        if (k < 64) v = W1[(3 + k) * 64 + n];
        else if (k < 67) v = W1[(k - 64) * 64 + n];
        W1t[n * 96 + k] = f2bf(v);
    } else if (t < T_W2) {
        const int i = t - T_W1;
        const int n = i >> 6, k = i & 63;
        W2t[n * 64 + k] = f2bf(W2[k * 64 + n]);
    } else if (t < T_W3) {
        const int i = t - T_W2;
        const int n = i >> 6, k = i & 63;
        W3t[n * 64 + k] = f2bf(W3[k * 128 + n]);
    } else if (t < T_NXYZ) {
        const int i = t - T_W3;              // new_xyz = xyz[:, :SS] copy
        const int b = i / (SS * 3), j = i - b * (SS * 3);
        out_xyz[i] = xyz[(size_t)b * NN * 3 + j];
    } else if (t < T_SIDX) {
        const int i = t - T_NXYZ;
        out_sidx[i] = (float)(i & (SS - 1));
    }
}

// ---------------------------------------------------------------------------
// prep_feat: [B][C][N] fp32 -> [B][N][C] bf16 (coalesced reads per channel).
// ---------------------------------------------------------------------------
__global__ __launch_bounds__(256) void prep_feat(const float* __restrict__ feat,
                                                 ushort* __restrict__ feat_nc) {
    const int t = blockIdx.x * 256 + threadIdx.x;   // 0 .. BB*NN-1
    const int b = t >> 14, n = t & (NN - 1);
    const float* fb = feat + (size_t)b * CC * NN + n;
    ushort* dst = feat_nc + (size_t)t * 64;
    #pragma unroll
    for (int c8 = 0; c8 < 8; ++c8) {
        uint u[4];
        #pragma unroll
        for (int j = 0; j < 4; ++j) {
            const float f0 = fb[(size_t)(c8 * 8 + 2 * j) * NN];
            const float f1 = fb[(size_t)(c8 * 8 + 2 * j + 1) * NN];
            u[j] = (uint)f2bf(f0) | ((uint)f2bf(f1) << 16);
        }
        *(uint4*)(dst + c8 * 8) = make_uint4(u[0], u[1], u[2], u[3]);
    }
}

// ---------------------------------------------------------------------------
// bq: STATIC one wave per centroid (measured best: R4=55us vs dynamic 63/147).
// NEW: wave-uniform zero-hit guard — ~85% of iterations (esp. full-scan
// stragglers) have no hit at all; skip all mask/position bookkeeping there.
// 256-pt chunks with next-chunk prefetch issued before the dependent break.
// ---------------------------------------------------------------------------
__global__ __launch_bounds__(256) void bq_kernel(const float4* __restrict__ pts4,
                                                 int* __restrict__ idx_ws) {
    const int w = threadIdx.x >> 6, lane = threadIdx.x & 63;
    const int sg = blockIdx.x * 4 + w;       // 0 .. BB*SS-1
    const int b = sg >> 12, s = sg & (SS - 1);

    __shared__ int hits[4][KK];
    int* hit = hits[w];
    const unsigned long long ltmask = (1ull << lane) - 1ull;

    const float4* pb = pts4 + (size_t)b * NN;
    const float4 c = pb[s];

    float4 p0 = pb[lane], p1 = pb[64 + lane];
    float4 p2 = pb[128 + lane], p3 = pb[192 + lane];
    int cnt = 0;
    for (int base = 0;;) {
        const int nb = base + 256;
        const bool last = nb >= NN;
        const int pf = last ? 0 : nb;
        // prefetch next chunk (independent of this chunk's ballot/break)
        const float4 q0 = pb[pf + lane], q1 = pb[pf + 64 + lane];
        const float4 q2 = pb[pf + 128 + lane], q3 = pb[pf + 192 + lane];

        const float d0 = c.w + p0.w - 2.0f * (c.x * p0.x + c.y * p0.y + c.z * p0.z);
        const float d1 = c.w + p1.w - 2.0f * (c.x * p1.x + c.y * p1.y + c.z * p1.z);
        const float d2 = c.w + p2.w - 2.0f * (c.x * p2.x + c.y * p2.y + c.z * p2.z);
        const float d3 = c.w + p3.w - 2.0f * (c.x * p3.x + c.y * p3.y + c.z * p3.z);
        const bool h0 = d0 < R2, h1 = d1 < R2, h2 = d2 < R2, h3 = d3 < R2;
        const unsigned long long m0 = __ballot(h0), m1 = __ballot(h1);
        const unsigned long long m2 = __ballot(h2), m3 = __ballot(h3);
        if ((m0 | m1 | m2 | m3) != 0ull) {     // wave-uniform: skip when no hits
            const int c0 = __popcll(m0), c1 = __popcll(m1);
            const int c2 = __popcll(m2), c3 = __popcll(m3);
            if (h0) { const int p = cnt + __popcll(m0 & ltmask);                if (p < KK) hit[p] = base + lane; }
            if (h1) { const int p = cnt + c0 + __popcll(m1 & ltmask);           if (p < KK) hit[p] = base + 64 + lane; }
            if (h2) { const int p = cnt + c0 + c1 + __popcll(m2 & ltmask);      if (p < KK) hit[p] = base + 128 + lane; }
            if (h3) { const int p = cnt + c0 + c1 + c2 + __popcll(m3 & ltmask); if (p < KK) hit[p] = base + 192 + lane; }
            cnt += c0 + c1 + c2 + c3;
        }
        if (cnt >= KK || last) break;
        base = nb;
        p0 = q0; p1 = q1; p2 = q2; p3 = q3;
    }
    if (lane < KK) {
        const int v = (cnt == 0) ? 0 : ((lane < cnt) ? hit[lane] : hit[0]);
        idx_ws[(size_t)sg * KK + lane] = v;
    }
}

// ---------------------------------------------------------------------------
// mlp: 512 blocks x 4 waves x 4 groups/wave (block owns 16 consecutive s).
// W1 frags pinned; W2/W3 streamed (L1-hot). Rolling 1-deep pipeline: next
// group's idx prefetched during layer1, its rows/pts during layers 2-3 —
// gather latency exposed only once per 4 groups. Fused transpose epilogue:
// pooled results -> LDS stage -> coalesced fp32 stores (kills tr_kernel and
// the extra output bf16 round). XCD swizzle: xcd 0-3 -> batch 0, 4-7 -> 1.
// ---------------------------------------------------------------------------
__global__ __launch_bounds__(256, 2) void mlp_kernel(
        const float4* __restrict__ pts4, const ushort* __restrict__ feat_nc,
        const ushort* __restrict__ W1t, const ushort* __restrict__ W2t,
        const ushort* __restrict__ W3t,
        const float* __restrict__ b1, const float* __restrict__ b2,
        const float* __restrict__ b3,
        const int* __restrict__ idx_ws, float* __restrict__ out_feat) {
    const int w = threadIdx.x >> 6, lane = threadIdx.x & 63;
    const int quad = lane >> 4, mrow = lane & 15;
    const int m = lane & 31, half = lane >> 5;

    __shared__ __align__(16) ushort ldsA[4][32 * 104];   // g -> h1 -> h2 per wave
    __shared__ float stage[128][20];                     // [ch][16 s + pad]
    ushort* gbuf = ldsA[w];

    // W1 fragments pinned
    bf16x8 w1f[4][3];
    #pragma unroll
    for (int nt = 0; nt < 4; ++nt)
        #pragma unroll
        for (int ks = 0; ks < 3; ++ks)
            w1f[nt][ks] = *(const bf16x8*)(W1t + (nt * 16 + mrow) * 96 + ks * 32 + quad * 8);
    float bias1[4], bias2[4], bias3[8];
    #pragma unroll
    for (int nt = 0; nt < 4; ++nt) {
        bias1[nt] = b1[nt * 16 + mrow];
        bias2[nt] = b2[nt * 16 + mrow];
    }
    #pragma unroll
    for (int nt = 0; nt < 8; ++nt) bias3[nt] = b3[nt * 16 + mrow];

    // block -> (batch, s-range) swizzle; block owns 16 consecutive s
    const int xcd = blockIdx.x & 7;
    const int j = blockIdx.x >> 3;                 // 0..63
    const int b = xcd >> 2;
    const int sbase = (xcd & 3) * 1024 + j * 16;   // block's 16-s tile
    const int s0 = sbase + w * 4;                  // wave's 4 consecutive s
    const int grp0 = b * SS + s0;
    const float4* pbase = pts4 + (size_t)b * NN;
    const ushort* fbase = feat_nc + (size_t)b * NN * 64;

    // prologue: stage group 0 into registers
    int sid = idx_ws[(size_t)grp0 * KK + m];
    uint4 stg[4];
    {
        const ushort* src = fbase + (size_t)sid * 64 + half * 32;
        #pragma unroll
        for (int i = 0; i < 4; ++i) stg[i] = *(const uint4*)(src + i * 8);
    }
    float4 sp = pbase[sid];
    float4 scc = pbase[s0];

    #pragma unroll
    for (int gi = 0; gi < 4; ++gi) {
        const int grp = grp0 + gi;

        // ---- stage registers -> LDS ----------------------------------------
        {
            ushort* dst = gbuf + m * 104 + half * 32;
            #pragma unroll
            for (int i = 0; i < 4; ++i) *(uint4*)(dst + i * 8) = stg[i];
            if (half == 0) {
                bf16x8 rel = {(__bf16)(sp.x - scc.x), (__bf16)(sp.y - scc.y),
                              (__bf16)(sp.z - scc.z), (__bf16)0.f,
                              (__bf16)0.f, (__bf16)0.f, (__bf16)0.f, (__bf16)0.f};
                *(bf16x8*)(gbuf + m * 104 + 64) = rel;
                *(uint4*)(gbuf + m * 104 + 88) = make_uint4(0, 0, 0, 0);
            } else {
                *(uint4*)(gbuf + m * 104 + 72) = make_uint4(0, 0, 0, 0);
                *(uint4*)(gbuf + m * 104 + 80) = make_uint4(0, 0, 0, 0);
            }
        }

        // prefetch next group's idx (overlaps layer 1)
        int sid1 = 0;
        if (gi < 3) sid1 = idx_ws[(size_t)(grp + 1) * KK + m];

        // ---- layer 1: [32x96]x[96x64], W1 pinned; h1 overwrites g ----------
        {
            f32x4 acc[2][4];
            #pragma unroll
            for (int mt = 0; mt < 2; ++mt)
                #pragma unroll
                for (int nt = 0; nt < 4; ++nt)
                    acc[mt][nt] = (f32x4){bias1[nt], bias1[nt], bias1[nt], bias1[nt]};
            #pragma unroll
            for (int ks = 0; ks < 3; ++ks) {
                const bf16x8 a0 = *(const bf16x8*)(gbuf + mrow * 104 + ks * 32 + quad * 8);
                const bf16x8 a1 = *(const bf16x8*)(gbuf + (16 + mrow) * 104 + ks * 32 + quad * 8);
                #pragma unroll
                for (int nt = 0; nt < 4; ++nt) {
                    acc[0][nt] = MFMA(a0, w1f[nt][ks], acc[0][nt]);
                    acc[1][nt] = MFMA(a1, w1f[nt][ks], acc[1][nt]);
                }
            }
            #pragma unroll
            for (int mt = 0; mt < 2; ++mt)
                #pragma unroll
                for (int nt = 0; nt < 4; ++nt)
                    #pragma unroll
                    for (int r = 0; r < 4; ++r)
                        gbuf[(mt * 16 + quad * 4 + r) * 104 + nt * 16 + mrow] =
                            f2bf(fmaxf(acc[mt][nt][r], 0.0f));
        }

        // prefetch next group's rows + pts (overlaps layers 2-3)
        uint4 stg1[4];
        float4 sp1, scc1;
        if (gi < 3) {
            const ushort* src1 = fbase + (size_t)sid1 * 64 + half * 32;
            #pragma unroll
            for (int i = 0; i < 4; ++i) stg1[i] = *(const uint4*)(src1 + i * 8);
            sp1 = pbase[sid1];
            scc1 = pbase[s0 + gi + 1];
        }

        // ---- layer 2: [32x64]x[64x64], W2 streamed; h2 overwrites h1 -------
        {
            f32x4 acc[2][4];
            #pragma unroll
            for (int mt = 0; mt < 2; ++mt)
                #pragma unroll
                for (int nt = 0; nt < 4; ++nt)
                    acc[mt][nt] = (f32x4){bias2[nt], bias2[nt], bias2[nt], bias2[nt]};
            #pragma unroll
            for (int ks = 0; ks < 2; ++ks) {
                const bf16x8 a0 = *(const bf16x8*)(gbuf + mrow * 104 + ks * 32 + quad * 8);
                const bf16x8 a1 = *(const bf16x8*)(gbuf + (16 + mrow) * 104 + ks * 32 + quad * 8);
                #pragma unroll
                for (int nt = 0; nt < 4; ++nt) {
                    const bf16x8 wf = *(const bf16x8*)(W2t + (nt * 16 + mrow) * 64 + ks * 32 + quad * 8);
                    acc[0][nt] = MFMA(a0, wf, acc[0][nt]);
                    acc[1][nt] = MFMA(a1, wf, acc[1][nt]);
                }
            }
            #pragma unroll
            for (int mt = 0; mt < 2; ++mt)
                #pragma unroll
                for (int nt = 0; nt < 4; ++nt)
                    #pragma unroll
                    for (int r = 0; r < 4; ++r)
                        gbuf[(mt * 16 + quad * 4 + r) * 104 + nt * 16 + mrow] =
                            f2bf(fmaxf(acc[mt][nt][r], 0.0f));
        }

        // ---- layer 3: [32x64]x[64x128], W3 streamed; fused maxpool ---------
        {
            f32x4 acc[2][8];
            #pragma unroll
            for (int mt = 0; mt < 2; ++mt)
                #pragma unroll
                for (int nt = 0; nt < 8; ++nt)
                    acc[mt][nt] = (f32x4){bias3[nt], bias3[nt], bias3[nt], bias3[nt]};
            #pragma unroll
            for (int ks = 0; ks < 2; ++ks) {
                const bf16x8 a0 = *(const bf16x8*)(gbuf + mrow * 104 + ks * 32 + quad * 8);
                const bf16x8 a1 = *(const bf16x8*)(gbuf + (16 + mrow) * 104 + ks * 32 + quad * 8);
                #pragma unroll
                for (int nt = 0; nt < 8; ++nt) {
                    const bf16x8 wf = *(const bf16x8*)(W3t + (nt * 16 + mrow) * 64 + ks * 32 + quad * 8);
                    acc[0][nt] = MFMA(a0, wf, acc[0][nt]);
                    acc[1][nt] = MFMA(a1, wf, acc[1][nt]);
                }
            }
            const int sl = w * 4 + gi;         // slot within the block's 16 s
            #pragma unroll
            for (int nt = 0; nt < 8; ++nt) {
                const f32x4 v0 = acc[0][nt], v1 = acc[1][nt];
                float mx = fmaxf(fmaxf(v0[0], v0[1]), fmaxf(v0[2], v0[3]));
                mx = fmaxf(mx, fmaxf(fmaxf(v1[0], v1[1]), fmaxf(v1[2], v1[3])));
                mx = fmaxf(mx, __shfl_xor(mx, 16));
                mx = fmaxf(mx, __shfl_xor(mx, 32));
                mx = fmaxf(mx, 0.0f);
                if (quad == 0) stage[nt * 16 + mrow][sl] = mx;
            }
        }

        // rotate staging registers
        if (gi < 3) {
            sid = sid1;
            #pragma unroll
            for (int i = 0; i < 4; ++i) stg[i] = stg1[i];
            sp = sp1; scc = scc1;
        }
    }
    __syncthreads();

    // ---- fused transpose epilogue: 128 ch x 16 s, 8 floats per thread ------
    {
        const int ch = threadIdx.x >> 1;
        const int h8 = (threadIdx.x & 1) * 8;
        const float* srow = &stage[ch][h8];
        float* dst = out_feat + ((size_t)b * 128 + ch) * SS + sbase + h8;
        *(float4*)(dst + 0) = make_float4(srow[0], srow[1], srow[2], srow[3]);
        *(float4*)(dst + 4) = make_float4(srow[4], srow[5], srow[6], srow[7]);
    }
}

// ---------------------------------------------------------------------------
extern "C" void kernel_launch(void* const* d_in, const int* in_sizes, int n_in,
                              void* d_out, int out_size, void* d_ws, size_t ws_size,
                              hipStream_t stream) {
    const float* xyz  = (const float*)d_in[0];
    const float* feat = (const float*)d_in[1];
    const float* W1   = (const float*)d_in[2];
    const float* b1   = (const float*)d_in[3];
    const float* W2   = (const float*)d_in[4];
    const float* b2   = (const float*)d_in[5];
    const float* W3   = (const float*)d_in[6];
    const float* b3   = (const float*)d_in[7];

    float* out      = (float*)d_out;
    float* out_xyz  = out;                               // [2,4096,3]
    float* out_feat = out + (size_t)BB * SS * 3;         // [2,128,4096]
    float* out_sidx = out_feat + (size_t)BB * 128 * SS;  // [2,4096]

    char* ws = (char*)d_ws;
    int*    idx_ws  = (int*)(ws + WS_IDX);
    float4* pts4    = (float4*)(ws + WS_PTS4);
    ushort* feat_nc = (ushort*)(ws + WS_FEAT);
    ushort* W1t     = (ushort*)(ws + WS_W1T);
    ushort* W2t     = (ushort*)(ws + WS_W2T);
    ushort* W3t     = (ushort*)(ws + WS_W3T);

    prep_misc<<<(T_SIDX + 255) / 256, 256, 0, stream>>>(
        xyz, W1, W2, W3, pts4, W1t, W2t, W3t, out_xyz, out_sidx);
    prep_feat<<<BB * NN / 256, 256, 0, stream>>>(feat, feat_nc);
    bq_kernel<<<BB * SS / 4, 256, 0, stream>>>(pts4, idx_ws);
    mlp_kernel<<<512, 256, 0, stream>>>(pts4, feat_nc, W1t, W2t, W3t,
                                        b1, b2, b3, idx_ws, out_feat);
}